// Round 2
// baseline (10361.717 us; speedup 1.0000x reference)
//
#include <hip/hip_runtime.h>

#define NN 100000
#define NE 1600000
#define NG 64

// swizzled k-major tile index, 64-wide m dimension
__device__ __forceinline__ int swz_idx(int k, int m) {
  return k * 64 + ((((m >> 2) ^ (k & 15)) << 2) | (m & 3));
}

__device__ __forceinline__ float wave_sum(float v) {
#pragma unroll
  for (int off = 32; off; off >>= 1) v += __shfl_down(v, off, 64);
  return v;
}
__device__ __forceinline__ float wave_max(float v) {
#pragma unroll
  for (int off = 32; off; off >>= 1) v = fmaxf(v, __shfl_down(v, off, 64));
  return v;
}

// ---------- GEMM with B streamed from cache: C[m,0:128] = X'[m,0:KD] @ B ----------
// X' row m = X[rowidx[m]] (gather) or X[m]. B row-stride ldb. Used for h0.
template <int KD>
__global__ void __launch_bounds__(256)
gemm_cacheB(const float* __restrict__ X, const int* __restrict__ rowidx,
            const float* __restrict__ B, int ldb, const float* __restrict__ bias,
            float* __restrict__ C, float* __restrict__ C2, int M) {
  __shared__ float xs[KD * 64];
  constexpr int KC = KD / 4;
  const int tid = threadIdx.x;
  const int bm = blockIdx.x * 64;

  for (int idx = tid; idx < 64 * KC; idx += 256) {
    int m = idx / KC, c = idx - m * KC;
    int gm = bm + m;
    float4 v = make_float4(0.f, 0.f, 0.f, 0.f);
    if (gm < M) {
      int r = rowidx ? rowidx[gm] : gm;
      v = *(const float4*)(X + (size_t)r * KD + 4 * c);
    }
    int k0 = 4 * c;
    xs[swz_idx(k0 + 0, m)] = v.x;
    xs[swz_idx(k0 + 1, m)] = v.y;
    xs[swz_idx(k0 + 2, m)] = v.z;
    xs[swz_idx(k0 + 3, m)] = v.w;
  }
  __syncthreads();

  const int tx = tid & 15, ty = tid >> 4;
  float acc[4][8] = {};
#pragma unroll 4
  for (int k = 0; k < KD; ++k) {
    float4 a = *(float4*)(xs + k * 64 + ((ty ^ (k & 15)) << 2));
    float4 b0 = *(const float4*)(B + (size_t)k * ldb + 4 * tx);
    float4 b1 = *(const float4*)(B + (size_t)k * ldb + 64 + 4 * tx);
    float av[4] = {a.x, a.y, a.z, a.w};
    float bv[8] = {b0.x, b0.y, b0.z, b0.w, b1.x, b1.y, b1.z, b1.w};
#pragma unroll
    for (int i = 0; i < 4; ++i)
#pragma unroll
      for (int j = 0; j < 8; ++j) acc[i][j] += av[i] * bv[j];
  }

#pragma unroll
  for (int i = 0; i < 4; ++i) {
    int gm = bm + 4 * ty + i;
    if (gm >= M) continue;
    float4 o0, o1;
    o0.x = acc[i][0] + bias[4 * tx + 0];
    o0.y = acc[i][1] + bias[4 * tx + 1];
    o0.z = acc[i][2] + bias[4 * tx + 2];
    o0.w = acc[i][3] + bias[4 * tx + 3];
    o1.x = acc[i][4] + bias[64 + 4 * tx + 0];
    o1.y = acc[i][5] + bias[64 + 4 * tx + 1];
    o1.z = acc[i][6] + bias[64 + 4 * tx + 2];
    o1.w = acc[i][7] + bias[64 + 4 * tx + 3];
    *(float4*)(C + (size_t)gm * 128 + 4 * tx) = o0;
    *(float4*)(C + (size_t)gm * 128 + 64 + 4 * tx) = o1;
    if (C2) {
      *(float4*)(C2 + (size_t)gm * 128 + 4 * tx) = o0;
      *(float4*)(C2 + (size_t)gm * 128 + 64 + 4 * tx) = o1;
    }
  }
}

// ---------- fused message pass: a[n] = sum_k Wmsg_k @ (sum_{e in CSR_k[n]} h[src]) + deg_k*b_k ----------
__global__ void __launch_bounds__(256)
msg_kernel(const float* __restrict__ h, const int* __restrict__ rowst3,
           const int* __restrict__ deg3, const int* __restrict__ payload,
           const float* __restrict__ WmsgT, const float* __restrict__ bmsg,
           float* __restrict__ a) {
  __shared__ float xs[128 * 64];  // k-major swizzled pre-aggregated tile
  const int tid = threadIdx.x;
  const int lane = tid & 63, wid = tid >> 6;
  const int bm = blockIdx.x * 64;
  const int tx = tid & 15, ty = tid >> 4;
  float acc[4][8] = {};

  for (int et = 0; et < 3; ++et) {
    // gather: each wave aggregates 16 nodes, full 128-wide rows (2 floats/lane)
    for (int nn = 0; nn < 16; ++nn) {
      int m = wid * 16 + nn;
      int gn = bm + m;
      float sx = 0.f, sy = 0.f;
      if (gn < NN) {
        int b3 = gn * 3 + et;
        int s = rowst3[b3], d = deg3[b3];
        for (int i = 0; i < d; ++i) {
          int src = payload[s + i];
          float2 v = *(const float2*)(h + (size_t)src * 128 + 2 * lane);
          sx += v.x;
          sy += v.y;
        }
      }
      xs[swz_idx(2 * lane + 0, m)] = sx;
      xs[swz_idx(2 * lane + 1, m)] = sy;
    }
    __syncthreads();

    const float* B = WmsgT + et * 128;  // [128][384] panel
#pragma unroll 4
    for (int k = 0; k < 128; ++k) {
      float4 av4 = *(float4*)(xs + k * 64 + ((ty ^ (k & 15)) << 2));
      float4 b0 = *(const float4*)(B + (size_t)k * 384 + 4 * tx);
      float4 b1 = *(const float4*)(B + (size_t)k * 384 + 64 + 4 * tx);
      float av[4] = {av4.x, av4.y, av4.z, av4.w};
      float bv[8] = {b0.x, b0.y, b0.z, b0.w, b1.x, b1.y, b1.z, b1.w};
#pragma unroll
      for (int i = 0; i < 4; ++i)
#pragma unroll
        for (int j = 0; j < 8; ++j) acc[i][j] += av[i] * bv[j];
    }
    __syncthreads();
  }

#pragma unroll
  for (int i = 0; i < 4; ++i) {
    int gm = bm + 4 * ty + i;
    if (gm >= NN) continue;
    float d0 = (float)deg3[gm * 3 + 0];
    float d1 = (float)deg3[gm * 3 + 1];
    float d2 = (float)deg3[gm * 3 + 2];
    float4 o0, o1;
    float* po0 = &o0.x;
    float* po1 = &o1.x;
#pragma unroll
    for (int j = 0; j < 4; ++j) {
      int c0 = 4 * tx + j, c1 = 64 + 4 * tx + j;
      po0[j] = acc[i][j] + d0 * bmsg[c0] + d1 * bmsg[128 + c0] + d2 * bmsg[256 + c0];
      po1[j] = acc[i][4 + j] + d0 * bmsg[c1] + d1 * bmsg[128 + c1] + d2 * bmsg[256 + c1];
    }
    *(float4*)(a + (size_t)gm * 128 + 4 * tx) = o0;
    *(float4*)(a + (size_t)gm * 128 + 64 + 4 * tx) = o1;
  }
}

// ---------- fused GRU: gi = a@WihT, gh = h@WhhT, gates, h updated in place ----------
__global__ void __launch_bounds__(256)
gru_kernel(float* __restrict__ h, const float* __restrict__ a,
           const float* __restrict__ WihT, const float* __restrict__ WhhT,
           const float* __restrict__ bih, const float* __restrict__ bhh, int M) {
  extern __shared__ float lds[];
  float* as_ = lds;            // [128][64] swz
  float* hs = lds + 128 * 64;  // [128][64] swz
  const int tid = threadIdx.x;
  const int bm = blockIdx.x * 64;

  for (int idx = tid; idx < 64 * 32; idx += 256) {
    int m = idx >> 5, c = idx & 31;
    int gm = bm + m;
    float4 va = make_float4(0.f, 0.f, 0.f, 0.f);
    float4 vh = make_float4(0.f, 0.f, 0.f, 0.f);
    if (gm < M) {
      va = *(const float4*)(a + (size_t)gm * 128 + 4 * c);
      vh = *(const float4*)(h + (size_t)gm * 128 + 4 * c);
    }
    int k0 = 4 * c;
    as_[swz_idx(k0 + 0, m)] = va.x;
    as_[swz_idx(k0 + 1, m)] = va.y;
    as_[swz_idx(k0 + 2, m)] = va.z;
    as_[swz_idx(k0 + 3, m)] = va.w;
    hs[swz_idx(k0 + 0, m)] = vh.x;
    hs[swz_idx(k0 + 1, m)] = vh.y;
    hs[swz_idx(k0 + 2, m)] = vh.z;
    hs[swz_idx(k0 + 3, m)] = vh.w;
  }
  __syncthreads();

  const int tx = tid & 15, ty = tid >> 4;
  for (int j0 = 0; j0 < 128; j0 += 64) {
    float ai[3][4][4] = {};
    float ah[3][4][4] = {};
#pragma unroll 2
    for (int k = 0; k < 128; ++k) {
      int off = k * 64 + ((ty ^ (k & 15)) << 2);
      float4 af4 = *(float4*)(as_ + off);
      float4 hf4 = *(float4*)(hs + off);
      float af[4] = {af4.x, af4.y, af4.z, af4.w};
      float hf[4] = {hf4.x, hf4.y, hf4.z, hf4.w};
#pragma unroll
      for (int g = 0; g < 3; ++g) {
        float4 bi4 = *(const float4*)(WihT + (size_t)k * 384 + g * 128 + j0 + 4 * tx);
        float4 bh4 = *(const float4*)(WhhT + (size_t)k * 384 + g * 128 + j0 + 4 * tx);
        float bi[4] = {bi4.x, bi4.y, bi4.z, bi4.w};
        float bh[4] = {bh4.x, bh4.y, bh4.z, bh4.w};
#pragma unroll
        for (int i = 0; i < 4; ++i)
#pragma unroll
          for (int j = 0; j < 4; ++j) {
            ai[g][i][j] += af[i] * bi[j];
            ah[g][i][j] += hf[i] * bh[j];
          }
      }
    }
#pragma unroll
    for (int i = 0; i < 4; ++i) {
      int m = 4 * ty + i;
      int gm = bm + m;
      if (gm >= M) continue;
      float o[4];
#pragma unroll
      for (int j = 0; j < 4; ++j) {
        int jj = j0 + 4 * tx + j;
        float ir = ai[0][i][j] + bih[jj];
        float iz = ai[1][i][j] + bih[128 + jj];
        float in_ = ai[2][i][j] + bih[256 + jj];
        float hr = ah[0][i][j] + bhh[jj];
        float hz = ah[1][i][j] + bhh[128 + jj];
        float hn = ah[2][i][j] + bhh[256 + jj];
        float r = 1.f / (1.f + expf(-(ir + hr)));
        float z = 1.f / (1.f + expf(-(iz + hz)));
        float nv = tanhf(in_ + r * hn);
        float ho = hs[swz_idx(jj, m)];
        o[j] = (1.f - z) * nv + z * ho;
      }
      *(float4*)(h + (size_t)gm * 128 + j0 + 4 * tx) =
          make_float4(o[0], o[1], o[2], o[3]);
    }
  }
}

// ---------- CSR build keyed by (dst, etype) ----------
__global__ void count3_k(const int* __restrict__ dst, const int* __restrict__ et,
                         int* __restrict__ deg3) {
  int e = blockIdx.x * 256 + threadIdx.x;
  if (e < NE) atomicAdd(&deg3[dst[e] * 3 + et[e]], 1);
}
__global__ void scan1(const int* __restrict__ deg, int* __restrict__ rowst,
                      int* __restrict__ csum, int L) {
  __shared__ int s[256];
  int base = blockIdx.x * 1024;
  int tid = threadIdx.x;
  int v[4], pre[4];
  int run = 0;
#pragma unroll
  for (int j = 0; j < 4; ++j) {
    int idx = base + tid * 4 + j;
    v[j] = (idx < L) ? deg[idx] : 0;
    pre[j] = run;
    run += v[j];
  }
  s[tid] = run;
  __syncthreads();
  for (int off = 1; off < 256; off <<= 1) {
    int t = (tid >= off) ? s[tid - off] : 0;
    __syncthreads();
    s[tid] += t;
    __syncthreads();
  }
  int excl = (tid == 0) ? 0 : s[tid - 1];
#pragma unroll
  for (int j = 0; j < 4; ++j) {
    int idx = base + tid * 4 + j;
    if (idx < L) rowst[idx] = excl + pre[j];
  }
  if (tid == 255) csum[blockIdx.x] = s[255];
}
__global__ void scan2(int* csum, int nch) {
  if (threadIdx.x == 0 && blockIdx.x == 0) {
    int run = 0;
    for (int i = 0; i < nch; ++i) { int t = csum[i]; csum[i] = run; run += t; }
  }
}
__global__ void scan3(int* rowst, const int* __restrict__ csum, int L) {
  int idx = blockIdx.x * 256 + threadIdx.x;
  if (idx < L) rowst[idx] += csum[idx >> 10];
}
__global__ void fill3_k(const int* __restrict__ src, const int* __restrict__ dst,
                        const int* __restrict__ et, const int* __restrict__ rowst3,
                        int* __restrict__ cursor3, int* __restrict__ payload) {
  int e = blockIdx.x * 256 + threadIdx.x;
  if (e >= NE) return;
  int b3 = dst[e] * 3 + et[e];
  int pos = rowst3[b3] + atomicAdd(&cursor3[b3], 1);
  payload[pos] = src[e];
}

// ---------- misc ----------
__global__ void transpose_w(const float* __restrict__ W, float* __restrict__ WT,
                            int J, int Kd) {
  int idx = blockIdx.x * 256 + threadIdx.x;
  if (idx >= J * Kd) return;
  int j = idx / Kd, k = idx - j * Kd;
  WT[(size_t)k * J + j] = W[idx];
}

__global__ void __launch_bounds__(256)
gate_k(const float* __restrict__ h, const float* __restrict__ h0,
       const float* __restrict__ Wg, const float* __restrict__ bg,
       float* __restrict__ gate) {
  int wid = threadIdx.x >> 6, lane = threadIdx.x & 63;
  int n = blockIdx.x * 4 + wid;
  if (n >= NN) return;
  float2 hv = *(const float2*)(h + (size_t)n * 128 + 2 * lane);
  float2 h0v = *(const float2*)(h0 + (size_t)n * 128 + 2 * lane);
  float p = hv.x * Wg[2 * lane] + hv.y * Wg[2 * lane + 1] +
            h0v.x * Wg[128 + 2 * lane] + h0v.y * Wg[128 + 2 * lane + 1];
  p = wave_sum(p);
  if (lane == 0) gate[n] = p + bg[0];
}

__global__ void bounds_k(const int* __restrict__ gid, int* __restrict__ bound) {
  int g = threadIdx.x;
  if (g > NG) return;
  int lo = 0, hi = NN;
  while (lo < hi) {
    int mid = (lo + hi) >> 1;
    if (gid[mid] < g) lo = mid + 1; else hi = mid;
  }
  bound[g] = lo;
}

__global__ void __launch_bounds__(256)
pool_k(const float* __restrict__ h, const float* __restrict__ h0,
       const float* __restrict__ gate, const int* __restrict__ bound,
       const float* __restrict__ Wout, const float* __restrict__ bout,
       float* __restrict__ out) {
  int g = blockIdx.x;
  int s = bound[g], e = bound[g + 1];
  __shared__ float sred[4];
  __shared__ float sbc[2];
  __shared__ float facc[1024];
  int tid = threadIdx.x, wid = tid >> 6, lane = tid & 63;
  if (s >= e) { if (tid == 0) out[g] = bout[0]; return; }

  float mx = -3.4e38f;
  for (int i = s + tid; i < e; i += 256) mx = fmaxf(mx, gate[i]);
  mx = wave_max(mx);
  if (lane == 0) sred[wid] = mx;
  __syncthreads();
  if (tid == 0) sbc[0] = fmaxf(fmaxf(sred[0], sred[1]), fmaxf(sred[2], sred[3]));
  __syncthreads();
  float mglob = sbc[0];

  float ss = 0.f;
  for (int i = s + tid; i < e; i += 256) ss += expf(gate[i] - mglob);
  ss = wave_sum(ss);
  if (lane == 0) sred[wid] = ss;
  __syncthreads();
  if (tid == 0) sbc[1] = sred[0] + sred[1] + sred[2] + sred[3];
  __syncthreads();
  float S = sbc[1];

  float a0 = 0.f, a1 = 0.f, a2 = 0.f, a3 = 0.f;
  for (int n = s + wid; n < e; n += 4) {
    float alpha = expf(gate[n] - mglob) / S;
    const float* p = (lane < 32) ? (h + (size_t)n * 128 + 4 * lane)
                                 : (h0 + (size_t)n * 128 + 4 * (lane - 32));
    float4 v = *(const float4*)p;
    a0 += alpha * v.x; a1 += alpha * v.y; a2 += alpha * v.z; a3 += alpha * v.w;
  }
  facc[wid * 256 + 4 * lane + 0] = a0;
  facc[wid * 256 + 4 * lane + 1] = a1;
  facc[wid * 256 + 4 * lane + 2] = a2;
  facc[wid * 256 + 4 * lane + 3] = a3;
  __syncthreads();
  float rsum = facc[tid] + facc[256 + tid] + facc[512 + tid] + facc[768 + tid];
  float val = rsum * Wout[tid];
  val = wave_sum(val);
  if (lane == 0) sred[wid] = val;
  __syncthreads();
  if (tid == 0) out[g] = sred[0] + sred[1] + sred[2] + sred[3] + bout[0];
}

// ---------- host ----------
extern "C" void kernel_launch(void* const* d_in, const int* in_sizes, int n_in,
                              void* d_out, int out_size, void* d_ws, size_t ws_size,
                              hipStream_t stream) {
  (void)in_sizes; (void)n_in; (void)out_size; (void)ws_size;
  const int* type_ids = (const int*)d_in[0];
  const int* src      = (const int*)d_in[1];
  const int* dst      = (const int*)d_in[2];
  const int* etypes   = (const int*)d_in[3];
  const int* gid      = (const int*)d_in[4];
  const float* embed  = (const float*)d_in[5];
  const float* W_red  = (const float*)d_in[6];
  const float* b_red  = (const float*)d_in[7];
  const float* W_msg  = (const float*)d_in[8];
  const float* b_msg  = (const float*)d_in[9];
  const float* W_ih   = (const float*)d_in[10];
  const float* b_ih   = (const float*)d_in[11];
  const float* W_hh   = (const float*)d_in[12];
  const float* b_hh   = (const float*)d_in[13];
  const float* W_gate = (const float*)d_in[14];
  const float* b_gate = (const float*)d_in[15];
  const float* W_out  = (const float*)d_in[16];
  const float* b_out  = (const float*)d_in[17];

  char* p = (char*)d_ws;
  auto take = [&](size_t nb) { char* r = p; p += (nb + 255) & ~(size_t)255; return r; };
  float* abuf  = (float*)take((size_t)NN * 128 * sizeof(float));
  float* hbuf  = (float*)take((size_t)NN * 128 * sizeof(float));
  float* h0b   = (float*)take((size_t)NN * 128 * sizeof(float));
  float* WmsgT = (float*)take(128 * 384 * sizeof(float));
  float* WihT  = (float*)take(128 * 384 * sizeof(float));
  float* WhhT  = (float*)take(128 * 384 * sizeof(float));
  float* WredT = (float*)take(64 * 128 * sizeof(float));
  float* gateb = (float*)take((size_t)NN * sizeof(float));
  int* deg3    = (int*)take((size_t)2 * 3 * NN * sizeof(int));
  int* cursor3 = deg3 + 3 * NN;
  int* rowst3  = (int*)take((size_t)3 * NN * sizeof(int));
  int* payload = (int*)take((size_t)NE * sizeof(int));
  int* csum    = (int*)take(2048);
  int* bound   = (int*)take(512);

  // weight transposes (k-major layouts for B operands)
  transpose_w<<<(128 * 64 + 255) / 256, 256, 0, stream>>>(W_red, WredT, 128, 64);
  transpose_w<<<(384 * 128 + 255) / 256, 256, 0, stream>>>(W_msg, WmsgT, 384, 128);
  transpose_w<<<(384 * 128 + 255) / 256, 256, 0, stream>>>(W_ih, WihT, 384, 128);
  transpose_w<<<(384 * 128 + 255) / 256, 256, 0, stream>>>(W_hh, WhhT, 384, 128);

  // CSR keyed by (dst, etype)
  const int L3 = 3 * NN;
  hipMemsetAsync(deg3, 0, (size_t)2 * L3 * sizeof(int), stream);
  count3_k<<<(NE + 255) / 256, 256, 0, stream>>>(dst, etypes, deg3);
  int nch = (L3 + 1023) / 1024;
  scan1<<<nch, 256, 0, stream>>>(deg3, rowst3, csum, L3);
  scan2<<<1, 64, 0, stream>>>(csum, nch);
  scan3<<<(L3 + 255) / 256, 256, 0, stream>>>(rowst3, csum, L3);
  fill3_k<<<(NE + 255) / 256, 256, 0, stream>>>(src, dst, etypes, rowst3, cursor3, payload);

  // h0 = embed[type_ids] @ W_red^T + b_red ; h = h0
  gemm_cacheB<64><<<(NN + 63) / 64, 256, 0, stream>>>(
      embed, type_ids, WredT, 128, b_red, h0b, hbuf, NN);

  for (int s6 = 0; s6 < 6; ++s6) {
    msg_kernel<<<(NN + 63) / 64, 256, 0, stream>>>(
        hbuf, rowst3, deg3, payload, WmsgT, b_msg, abuf);
    gru_kernel<<<(NN + 63) / 64, 256, 65536, stream>>>(
        hbuf, abuf, WihT, WhhT, b_ih, b_hh, NN);
  }

  gate_k<<<(NN + 3) / 4, 256, 0, stream>>>(hbuf, h0b, W_gate, b_gate, gateb);
  bounds_k<<<1, 128, 0, stream>>>(gid, bound);
  pool_k<<<NG, 256, 0, stream>>>(hbuf, h0b, gateb, bound, W_out, b_out, (float*)d_out);
}

// Round 3
// 2991.485 us; speedup vs baseline: 3.4637x; 3.4637x over previous
//
#include <hip/hip_runtime.h>

#define NN 100000
#define NE 1600000
#define NG 64

typedef __attribute__((ext_vector_type(8))) short bf16x8;
typedef __attribute__((ext_vector_type(4))) float f32x4;

__device__ __forceinline__ unsigned short f2bf(float f) {
  unsigned u = __float_as_uint(f);
  unsigned r = u + 0x7FFFu + ((u >> 16) & 1u);
  return (unsigned short)(r >> 16);
}
__device__ __forceinline__ float bf2f(unsigned u16) {
  return __uint_as_float(u16 << 16);
}

__device__ __forceinline__ float wave_sum(float v) {
#pragma unroll
  for (int off = 32; off; off >>= 1) v += __shfl_down(v, off, 64);
  return v;
}
__device__ __forceinline__ float wave_max(float v) {
#pragma unroll
  for (int off = 32; off; off >>= 1) v = fmaxf(v, __shfl_down(v, off, 64));
  return v;
}

// read one MFMA fragment (16B) from a swizzled [rows][256B] LDS tile image
__device__ __forceinline__ bf16x8 frag_ld(const char* base, int row, int kbyte) {
  return *(const bf16x8*)(base + row * 256 + (kbyte ^ ((row & 7) << 4)));
}

// ---------------- fused message pass (MFMA) ----------------
// a[n,:] = sum_et Wmsg_et @ (sum_{e in CSR(n,et)} h_bf[src]) + sum_et deg_et(n)*b_msg[et]
__global__ void __launch_bounds__(256)
msg_mfma(const unsigned short* __restrict__ hbf, const int* __restrict__ rowst3,
         const int* __restrict__ deg3, const int* __restrict__ payload,
         const unsigned short* __restrict__ Wmsg, const float* __restrict__ bmsg,
         unsigned short* __restrict__ abf) {
  __shared__ char As[16384];  // 64 rows x 128 bf16, swizzled
  __shared__ char Bs[32768];  // 128 cols x 128 bf16, swizzled
  const int tid = threadIdx.x, lane = tid & 63, wid = tid >> 6;
  const int l15 = lane & 15, lhi = lane >> 4;
  const int bm = blockIdx.x * 64;
  const int wrow0 = (wid >> 1) * 32, wcol0 = (wid & 1) * 64;

  f32x4 acc[8];
#pragma unroll
  for (int f = 0; f < 8; ++f)
#pragma unroll
    for (int r = 0; r < 4; ++r) acc[f][r] = 0.f;

  for (int et = 0; et < 3; ++et) {
    __syncthreads();  // previous MFMA done reading As/Bs
    // gather: wave handles 16 nodes, one 256B row per node (4B/lane)
    for (int nn = 0; nn < 16; ++nn) {
      int m = wid * 16 + nn;
      int gn = bm + m;
      float sx = 0.f, sy = 0.f;
      if (gn < NN) {
        int b3 = gn * 3 + et;
        int s = rowst3[b3], d = deg3[b3];
        int i = 0;
        for (; i + 2 <= d; i += 2) {
          int s0 = payload[s + i], s1 = payload[s + i + 1];
          unsigned v0 = *(const unsigned*)(hbf + (size_t)s0 * 128 + 2 * lane);
          unsigned v1 = *(const unsigned*)(hbf + (size_t)s1 * 128 + 2 * lane);
          sx += bf2f(v0 & 0xffffu) + bf2f(v1 & 0xffffu);
          sy += bf2f(v0 >> 16) + bf2f(v1 >> 16);
        }
        if (i < d) {
          int s0 = payload[s + i];
          unsigned v0 = *(const unsigned*)(hbf + (size_t)s0 * 128 + 2 * lane);
          sx += bf2f(v0 & 0xffffu);
          sy += bf2f(v0 >> 16);
        }
      }
      unsigned pk = (unsigned)f2bf(sx) | ((unsigned)f2bf(sy) << 16);
      *(unsigned*)(As + m * 256 + ((lane * 4) ^ ((m & 7) << 4))) = pk;
    }
    // stage B panel (W_et, native [col][k] layout)
    {
      const char* wp = (const char*)(Wmsg + (size_t)et * 16384);
      for (int g = tid; g < 2048; g += 256) {
        int row = g >> 4, o = (g & 15) << 4;
        *(uint4*)(Bs + row * 256 + (o ^ ((row & 7) << 4))) =
            *(const uint4*)(wp + row * 256 + o);
      }
    }
    __syncthreads();
#pragma unroll
    for (int ks = 0; ks < 4; ++ks) {
      int kb = ks * 64 + lhi * 16;
      bf16x8 af[2];
#pragma unroll
      for (int mf = 0; mf < 2; ++mf) af[mf] = frag_ld(As, wrow0 + mf * 16 + l15, kb);
#pragma unroll
      for (int nf = 0; nf < 4; ++nf) {
        bf16x8 bfr = frag_ld(Bs, wcol0 + nf * 16 + l15, kb);
#pragma unroll
        for (int mf = 0; mf < 2; ++mf)
          acc[mf * 4 + nf] = __builtin_amdgcn_mfma_f32_16x16x32_bf16(
              af[mf], bfr, acc[mf * 4 + nf], 0, 0, 0);
      }
    }
  }
  // epilogue: deg-weighted bias, store bf16
#pragma unroll
  for (int mf = 0; mf < 2; ++mf)
#pragma unroll
    for (int r = 0; r < 4; ++r) {
      int grow = bm + wrow0 + mf * 16 + lhi * 4 + r;
      if (grow >= NN) continue;
      float d0 = (float)deg3[grow * 3 + 0];
      float d1 = (float)deg3[grow * 3 + 1];
      float d2 = (float)deg3[grow * 3 + 2];
#pragma unroll
      for (int nf = 0; nf < 4; ++nf) {
        int col = wcol0 + nf * 16 + l15;
        float v = acc[mf * 4 + nf][r] + d0 * bmsg[col] + d1 * bmsg[128 + col] +
                  d2 * bmsg[256 + col];
        abf[(size_t)grow * 128 + col] = f2bf(v);
      }
    }
}

// ---------------- fused GRU (MFMA): gi = a@Wih^T, gh = h@Whh^T, gates, h in place ----------------
__global__ void __launch_bounds__(256)
gru_mfma(float* __restrict__ hf, unsigned short* __restrict__ hbf,
         const unsigned short* __restrict__ abf,
         const unsigned short* __restrict__ Wih, const unsigned short* __restrict__ Whh,
         const float* __restrict__ bih, const float* __restrict__ bhh) {
  __shared__ char As_a[16384];
  __shared__ char As_h[16384];
  __shared__ char Bs[32768];
  const int tid = threadIdx.x, lane = tid & 63, wid = tid >> 6;
  const int l15 = lane & 15, lhi = lane >> 4;
  const int bm = blockIdx.x * 64;
  const int wrow0 = (wid >> 1) * 32, wcol0 = (wid & 1) * 64;

  // stage both A tiles (a rows, h rows), swizzled
  for (int g = tid; g < 1024; g += 256) {
    int row = g >> 4, o = (g & 15) << 4;
    int gr = bm + row;
    uint4 va = make_uint4(0, 0, 0, 0), vh = make_uint4(0, 0, 0, 0);
    if (gr < NN) {
      va = *(const uint4*)((const char*)abf + (size_t)gr * 256 + o);
      vh = *(const uint4*)((const char*)hbf + (size_t)gr * 256 + o);
    }
    int so = o ^ ((row & 7) << 4);
    *(uint4*)(As_a + row * 256 + so) = va;
    *(uint4*)(As_h + row * 256 + so) = vh;
  }

  f32x4 rr[8], zz[8];
  for (int gate = 0; gate < 3; ++gate) {
    f32x4 acc_i[8], acc_h[8];
#pragma unroll
    for (int f = 0; f < 8; ++f)
#pragma unroll
      for (int r = 0; r < 4; ++r) { acc_i[f][r] = 0.f; acc_h[f][r] = 0.f; }

    // ---- gi partial: A = As_a, B = Wih panel ----
    __syncthreads();
    {
      const char* wp = (const char*)(Wih + (size_t)gate * 16384);
      for (int g = tid; g < 2048; g += 256) {
        int row = g >> 4, o = (g & 15) << 4;
        *(uint4*)(Bs + row * 256 + (o ^ ((row & 7) << 4))) =
            *(const uint4*)(wp + row * 256 + o);
      }
    }
    __syncthreads();
#pragma unroll
    for (int ks = 0; ks < 4; ++ks) {
      int kb = ks * 64 + lhi * 16;
      bf16x8 af[2];
#pragma unroll
      for (int mf = 0; mf < 2; ++mf) af[mf] = frag_ld(As_a, wrow0 + mf * 16 + l15, kb);
#pragma unroll
      for (int nf = 0; nf < 4; ++nf) {
        bf16x8 bfr = frag_ld(Bs, wcol0 + nf * 16 + l15, kb);
#pragma unroll
        for (int mf = 0; mf < 2; ++mf)
          acc_i[mf * 4 + nf] = __builtin_amdgcn_mfma_f32_16x16x32_bf16(
              af[mf], bfr, acc_i[mf * 4 + nf], 0, 0, 0);
      }
    }
    // ---- gh partial: A = As_h, B = Whh panel ----
    __syncthreads();
    {
      const char* wp = (const char*)(Whh + (size_t)gate * 16384);
      for (int g = tid; g < 2048; g += 256) {
        int row = g >> 4, o = (g & 15) << 4;
        *(uint4*)(Bs + row * 256 + (o ^ ((row & 7) << 4))) =
            *(const uint4*)(wp + row * 256 + o);
      }
    }
    __syncthreads();
#pragma unroll
    for (int ks = 0; ks < 4; ++ks) {
      int kb = ks * 64 + lhi * 16;
      bf16x8 af[2];
#pragma unroll
      for (int mf = 0; mf < 2; ++mf) af[mf] = frag_ld(As_h, wrow0 + mf * 16 + l15, kb);
#pragma unroll
      for (int nf = 0; nf < 4; ++nf) {
        bf16x8 bfr = frag_ld(Bs, wcol0 + nf * 16 + l15, kb);
#pragma unroll
        for (int mf = 0; mf < 2; ++mf)
          acc_h[mf * 4 + nf] = __builtin_amdgcn_mfma_f32_16x16x32_bf16(
              af[mf], bfr, acc_h[mf * 4 + nf], 0, 0, 0);
      }
    }

    if (gate < 2) {
#pragma unroll
      for (int mf = 0; mf < 2; ++mf)
#pragma unroll
        for (int nf = 0; nf < 4; ++nf) {
          int f = mf * 4 + nf;
          int col = wcol0 + nf * 16 + l15;
          float bi = bih[gate * 128 + col], bh = bhh[gate * 128 + col];
#pragma unroll
          for (int r = 0; r < 4; ++r) {
            float v = acc_i[f][r] + acc_h[f][r] + bi + bh;
            float sg = 1.f / (1.f + __expf(-v));
            if (gate == 0) rr[f][r] = sg;
            else zz[f][r] = sg;
          }
        }
    } else {
      // n-gate + blend + stores (fp32 master + bf16 shadow)
#pragma unroll
      for (int mf = 0; mf < 2; ++mf)
#pragma unroll
        for (int r = 0; r < 4; ++r) {
          int grow = bm + wrow0 + mf * 16 + lhi * 4 + r;
          if (grow >= NN) continue;
#pragma unroll
          for (int nf = 0; nf < 4; ++nf) {
            int f = mf * 4 + nf;
            int col = wcol0 + nf * 16 + l15;
            float in_ = acc_i[f][r] + bih[256 + col];
            float hn = acc_h[f][r] + bhh[256 + col];
            float x = in_ + rr[f][r] * hn;
            float e = __expf(-2.f * x);
            float n = (1.f - e) / (1.f + e);
            float z = zz[f][r];
            float ho = hf[(size_t)grow * 128 + col];
            float hv = (1.f - z) * n + z * ho;
            hf[(size_t)grow * 128 + col] = hv;
            hbf[(size_t)grow * 128 + col] = f2bf(hv);
          }
        }
    }
  }
}

// ---------- fp32 GEMM for h0 (B streamed from cache), from round 2 ----------
template <int KD>
__global__ void __launch_bounds__(256)
gemm_cacheB(const float* __restrict__ X, const int* __restrict__ rowidx,
            const float* __restrict__ B, int ldb, const float* __restrict__ bias,
            float* __restrict__ C, float* __restrict__ C2, int M) {
  __shared__ float xs[KD * 64];
  constexpr int KC = KD / 4;
  const int tid = threadIdx.x;
  const int bm = blockIdx.x * 64;

  for (int idx = tid; idx < 64 * KC; idx += 256) {
    int m = idx / KC, c = idx - m * KC;
    int gm = bm + m;
    float4 v = make_float4(0.f, 0.f, 0.f, 0.f);
    if (gm < M) {
      int r = rowidx ? rowidx[gm] : gm;
      v = *(const float4*)(X + (size_t)r * KD + 4 * c);
    }
    int k0 = 4 * c;
    int base = (k0 & ~15) * 64;
    int kk = k0 & 15;
    // simple swizzle: element (k,m) at [k*64 + (((m>>2)^(k&15))<<2 | (m&3))]
    xs[(k0 + 0) * 64 + ((((m >> 2) ^ ((kk + 0) & 15)) << 2) | (m & 3))] = v.x;
    xs[(k0 + 1) * 64 + ((((m >> 2) ^ ((kk + 1) & 15)) << 2) | (m & 3))] = v.y;
    xs[(k0 + 2) * 64 + ((((m >> 2) ^ ((kk + 2) & 15)) << 2) | (m & 3))] = v.z;
    xs[(k0 + 3) * 64 + ((((m >> 2) ^ ((kk + 3) & 15)) << 2) | (m & 3))] = v.w;
    (void)base;
  }
  __syncthreads();

  const int tx = tid & 15, ty = tid >> 4;
  float acc[4][8] = {};
#pragma unroll 4
  for (int k = 0; k < KD; ++k) {
    float4 a = *(float4*)(xs + k * 64 + ((ty ^ (k & 15)) << 2));
    float4 b0 = *(const float4*)(B + (size_t)k * ldb + 4 * tx);
    float4 b1 = *(const float4*)(B + (size_t)k * ldb + 64 + 4 * tx);
    float av[4] = {a.x, a.y, a.z, a.w};
    float bv[8] = {b0.x, b0.y, b0.z, b0.w, b1.x, b1.y, b1.z, b1.w};
#pragma unroll
    for (int i = 0; i < 4; ++i)
#pragma unroll
      for (int j = 0; j < 8; ++j) acc[i][j] += av[i] * bv[j];
  }

#pragma unroll
  for (int i = 0; i < 4; ++i) {
    int gm = bm + 4 * ty + i;
    if (gm >= M) continue;
    float4 o0, o1;
    o0.x = acc[i][0] + bias[4 * tx + 0];
    o0.y = acc[i][1] + bias[4 * tx + 1];
    o0.z = acc[i][2] + bias[4 * tx + 2];
    o0.w = acc[i][3] + bias[4 * tx + 3];
    o1.x = acc[i][4] + bias[64 + 4 * tx + 0];
    o1.y = acc[i][5] + bias[64 + 4 * tx + 1];
    o1.z = acc[i][6] + bias[64 + 4 * tx + 2];
    o1.w = acc[i][7] + bias[64 + 4 * tx + 3];
    *(float4*)(C + (size_t)gm * 128 + 4 * tx) = o0;
    *(float4*)(C + (size_t)gm * 128 + 64 + 4 * tx) = o1;
    if (C2) {
      *(float4*)(C2 + (size_t)gm * 128 + 4 * tx) = o0;
      *(float4*)(C2 + (size_t)gm * 128 + 64 + 4 * tx) = o1;
    }
  }
}

// ---------- CSR build keyed by (dst, etype) ----------
__global__ void count3_k(const int* __restrict__ dst, const int* __restrict__ et,
                         int* __restrict__ deg3) {
  int e = blockIdx.x * 256 + threadIdx.x;
  if (e < NE) atomicAdd(&deg3[dst[e] * 3 + et[e]], 1);
}
__global__ void scan1(const int* __restrict__ deg, int* __restrict__ rowst,
                      int* __restrict__ csum, int L) {
  __shared__ int s[256];
  int base = blockIdx.x * 1024;
  int tid = threadIdx.x;
  int v[4], pre[4];
  int run = 0;
#pragma unroll
  for (int j = 0; j < 4; ++j) {
    int idx = base + tid * 4 + j;
    v[j] = (idx < L) ? deg[idx] : 0;
    pre[j] = run;
    run += v[j];
  }
  s[tid] = run;
  __syncthreads();
  for (int off = 1; off < 256; off <<= 1) {
    int t = (tid >= off) ? s[tid - off] : 0;
    __syncthreads();
    s[tid] += t;
    __syncthreads();
  }
  int excl = (tid == 0) ? 0 : s[tid - 1];
#pragma unroll
  for (int j = 0; j < 4; ++j) {
    int idx = base + tid * 4 + j;
    if (idx < L) rowst[idx] = excl + pre[j];
  }
  if (tid == 255) csum[blockIdx.x] = s[255];
}
__global__ void scan2(int* csum, int nch) {
  if (threadIdx.x == 0 && blockIdx.x == 0) {
    int run = 0;
    for (int i = 0; i < nch; ++i) { int t = csum[i]; csum[i] = run; run += t; }
  }
}
__global__ void scan3(int* rowst, const int* __restrict__ csum, int L) {
  int idx = blockIdx.x * 256 + threadIdx.x;
  if (idx < L) rowst[idx] += csum[idx >> 10];
}
__global__ void fill3_k(const int* __restrict__ src, const int* __restrict__ dst,
                        const int* __restrict__ et, const int* __restrict__ rowst3,
                        int* __restrict__ cursor3, int* __restrict__ payload) {
  int e = blockIdx.x * 256 + threadIdx.x;
  if (e >= NE) return;
  int b3 = dst[e] * 3 + et[e];
  int pos = rowst3[b3] + atomicAdd(&cursor3[b3], 1);
  payload[pos] = src[e];
}

// ---------- misc ----------
__global__ void transpose_w(const float* __restrict__ W, float* __restrict__ WT,
                            int J, int Kd) {
  int idx = blockIdx.x * 256 + threadIdx.x;
  if (idx >= J * Kd) return;
  int j = idx / Kd, k = idx - j * Kd;
  WT[(size_t)k * J + j] = W[idx];
}

__global__ void conv_bf16v(const float* __restrict__ s, unsigned short* __restrict__ d,
                           int n4) {
  int i = blockIdx.x * 256 + threadIdx.x;
  if (i >= n4) return;
  float4 v = *(const float4*)(s + 4 * (size_t)i);
  unsigned lo = (unsigned)f2bf(v.x) | ((unsigned)f2bf(v.y) << 16);
  unsigned hi = (unsigned)f2bf(v.z) | ((unsigned)f2bf(v.w) << 16);
  *(unsigned*)(d + 4 * (size_t)i) = lo;
  *(unsigned*)(d + 4 * (size_t)i + 2) = hi;
}

__global__ void __launch_bounds__(256)
gate_k(const float* __restrict__ h, const float* __restrict__ h0,
       const float* __restrict__ Wg, const float* __restrict__ bg,
       float* __restrict__ gate) {
  int wid = threadIdx.x >> 6, lane = threadIdx.x & 63;
  int n = blockIdx.x * 4 + wid;
  if (n >= NN) return;
  float2 hv = *(const float2*)(h + (size_t)n * 128 + 2 * lane);
  float2 h0v = *(const float2*)(h0 + (size_t)n * 128 + 2 * lane);
  float p = hv.x * Wg[2 * lane] + hv.y * Wg[2 * lane + 1] +
            h0v.x * Wg[128 + 2 * lane] + h0v.y * Wg[128 + 2 * lane + 1];
  p = wave_sum(p);
  if (lane == 0) gate[n] = p + bg[0];
}

__global__ void bounds_k(const int* __restrict__ gid, int* __restrict__ bound) {
  int g = threadIdx.x;
  if (g > NG) return;
  int lo = 0, hi = NN;
  while (lo < hi) {
    int mid = (lo + hi) >> 1;
    if (gid[mid] < g) lo = mid + 1; else hi = mid;
  }
  bound[g] = lo;
}

__global__ void __launch_bounds__(256)
pool_k(const float* __restrict__ h, const float* __restrict__ h0,
       const float* __restrict__ gate, const int* __restrict__ bound,
       const float* __restrict__ Wout, const float* __restrict__ bout,
       float* __restrict__ out) {
  int g = blockIdx.x;
  int s = bound[g], e = bound[g + 1];
  __shared__ float sred[4];
  __shared__ float sbc[2];
  __shared__ float facc[1024];
  int tid = threadIdx.x, wid = tid >> 6, lane = tid & 63;
  if (s >= e) { if (tid == 0) out[g] = bout[0]; return; }

  float mx = -3.4e38f;
  for (int i = s + tid; i < e; i += 256) mx = fmaxf(mx, gate[i]);
  mx = wave_max(mx);
  if (lane == 0) sred[wid] = mx;
  __syncthreads();
  if (tid == 0) sbc[0] = fmaxf(fmaxf(sred[0], sred[1]), fmaxf(sred[2], sred[3]));
  __syncthreads();
  float mglob = sbc[0];

  float ss = 0.f;
  for (int i = s + tid; i < e; i += 256) ss += expf(gate[i] - mglob);
  ss = wave_sum(ss);
  if (lane == 0) sred[wid] = ss;
  __syncthreads();
  if (tid == 0) sbc[1] = sred[0] + sred[1] + sred[2] + sred[3];
  __syncthreads();
  float S = sbc[1];

  float a0 = 0.f, a1 = 0.f, a2 = 0.f, a3 = 0.f;
  for (int n = s + wid; n < e; n += 4) {
    float alpha = expf(gate[n] - mglob) / S;
    const float* p = (lane < 32) ? (h + (size_t)n * 128 + 4 * lane)
                                 : (h0 + (size_t)n * 128 + 4 * (lane - 32));
    float4 v = *(const float4*)p;
    a0 += alpha * v.x; a1 += alpha * v.y; a2 += alpha * v.z; a3 += alpha * v.w;
  }
  facc[wid * 256 + 4 * lane + 0] = a0;
  facc[wid * 256 + 4 * lane + 1] = a1;
  facc[wid * 256 + 4 * lane + 2] = a2;
  facc[wid * 256 + 4 * lane + 3] = a3;
  __syncthreads();
  float rsum = facc[tid] + facc[256 + tid] + facc[512 + tid] + facc[768 + tid];
  float val = rsum * Wout[tid];
  val = wave_sum(val);
  if (lane == 0) sred[wid] = val;
  __syncthreads();
  if (tid == 0) out[g] = sred[0] + sred[1] + sred[2] + sred[3] + bout[0];
}

// ---------- host ----------
extern "C" void kernel_launch(void* const* d_in, const int* in_sizes, int n_in,
                              void* d_out, int out_size, void* d_ws, size_t ws_size,
                              hipStream_t stream) {
  (void)in_sizes; (void)n_in; (void)out_size; (void)ws_size;
  const int* type_ids = (const int*)d_in[0];
  const int* src      = (const int*)d_in[1];
  const int* dst      = (const int*)d_in[2];
  const int* etypes   = (const int*)d_in[3];
  const int* gid      = (const int*)d_in[4];
  const float* embed  = (const float*)d_in[5];
  const float* W_red  = (const float*)d_in[6];
  const float* b_red  = (const float*)d_in[7];
  const float* W_msg  = (const float*)d_in[8];
  const float* b_msg  = (const float*)d_in[9];
  const float* W_ih   = (const float*)d_in[10];
  const float* b_ih   = (const float*)d_in[11];
  const float* W_hh   = (const float*)d_in[12];
  const float* b_hh   = (const float*)d_in[13];
  const float* W_gate = (const float*)d_in[14];
  const float* b_gate = (const float*)d_in[15];
  const float* W_out  = (const float*)d_in[16];
  const float* b_out  = (const float*)d_in[17];

  char* p = (char*)d_ws;
  auto take = [&](size_t nb) { char* r = p; p += (nb + 255) & ~(size_t)255; return r; };
  float* hf            = (float*)take((size_t)NN * 128 * sizeof(float));
  float* h0b           = (float*)take((size_t)NN * 128 * sizeof(float));
  unsigned short* hbf  = (unsigned short*)take((size_t)NN * 128 * 2);
  unsigned short* abf  = (unsigned short*)take((size_t)NN * 128 * 2);
  unsigned short* WmsgB = (unsigned short*)take(49152 * 2);
  unsigned short* WihB  = (unsigned short*)take(49152 * 2);
  unsigned short* WhhB  = (unsigned short*)take(49152 * 2);
  float* WredT = (float*)take(64 * 128 * sizeof(float));
  float* gateb = (float*)take((size_t)NN * sizeof(float));
  int* deg3    = (int*)take((size_t)2 * 3 * NN * sizeof(int));
  int* cursor3 = deg3 + 3 * NN;
  int* rowst3  = (int*)take((size_t)3 * NN * sizeof(int));
  int* payload = (int*)take((size_t)NE * sizeof(int));
  int* csum    = (int*)take(2048);
  int* bound   = (int*)take(512);

  // weight prep
  transpose_w<<<(128 * 64 + 255) / 256, 256, 0, stream>>>(W_red, WredT, 128, 64);
  conv_bf16v<<<(49152 / 4 + 255) / 256, 256, 0, stream>>>(W_msg, WmsgB, 49152 / 4);
  conv_bf16v<<<(49152 / 4 + 255) / 256, 256, 0, stream>>>(W_ih, WihB, 49152 / 4);
  conv_bf16v<<<(49152 / 4 + 255) / 256, 256, 0, stream>>>(W_hh, WhhB, 49152 / 4);

  // CSR keyed by (dst, etype)
  const int L3 = 3 * NN;
  hipMemsetAsync(deg3, 0, (size_t)2 * L3 * sizeof(int), stream);
  count3_k<<<(NE + 255) / 256, 256, 0, stream>>>(dst, etypes, deg3);
  int nch = (L3 + 1023) / 1024;
  scan1<<<nch, 256, 0, stream>>>(deg3, rowst3, csum, L3);
  scan2<<<1, 64, 0, stream>>>(csum, nch);
  scan3<<<(L3 + 255) / 256, 256, 0, stream>>>(rowst3, csum, L3);
  fill3_k<<<(NE + 255) / 256, 256, 0, stream>>>(src, dst, etypes, rowst3, cursor3, payload);

  // h0 = embed[type_ids] @ W_red^T + b_red ; h = h0 (fp32 master + bf16 shadow)
  gemm_cacheB<64><<<(NN + 63) / 64, 256, 0, stream>>>(
      embed, type_ids, WredT, 128, b_red, h0b, hf, NN);
  conv_bf16v<<<((NN * 128 / 4) + 255) / 256, 256, 0, stream>>>(hf, hbf, NN * 128 / 4);

  const int nblk = (NN + 63) / 64;
  for (int s6 = 0; s6 < 6; ++s6) {
    msg_mfma<<<nblk, 256, 0, stream>>>(hbf, rowst3, deg3, payload, WmsgB, b_msg, abf);
    gru_mfma<<<nblk, 256, 0, stream>>>(hf, hbf, abf, WihB, WhhB, b_ih, b_hh);
  }

  gate_k<<<(NN + 3) / 4, 256, 0, stream>>>(hf, h0b, W_gate, b_gate, gateb);
  bounds_k<<<1, 128, 0, stream>>>(gid, bound);
  pool_k<<<NG, 256, 0, stream>>>(hf, h0b, gateb, bound, W_out, b_out, (float*)d_out);
}